// Round 5
// baseline (171.790 us; speedup 1.0000x reference)
//
#include <hip/hip_runtime.h>

// Rec1_43748536877661 — diagonal SSM block, MI355X gfx950.
// B=2,S=2048,D=128,N=2048. fp32 in/out, bf16 MFMA compute (tol 2.14e-2).
// R5: single-pass fused proj+scan. 256 blocks (= batch x 16-n slice), 1 wave
// each, weights held in registers, h carried in-register across 128 t-tiles.
// Per tile: 12 MFMA + softplus/exp epilogue + 16-token in-wave scan (6 shfl)
// + LDS transpose -> packed A-frag y. 3 kernels total:
//  1. prep       pack x,W_B/dt/C,W_out fragment-linear bf16; Aval=-exp(A_log)
//  2. fusedscan  proj(B,dt,C) + full sequential scan -> ybp (bf16 A-frag)
//  3. outproj    y @ W_out^T + b_out -> fp32 out

#define BB 2
#define SS 2048
#define DDIM 128
#define NDIM 2048
#define TT (BB*SS)        // 4096 tokens
#define NTILE (TT/16)     // 256 t-tiles
#define TPB 128           // t-tiles per batch chain

typedef short short8 __attribute__((ext_vector_type(8)));
typedef float floatx4 __attribute__((ext_vector_type(4)));

__device__ __forceinline__ unsigned short f2b(float f){
  unsigned u = __float_as_uint(f);
  u += 0x7FFFu + ((u >> 16) & 1u);
  return (unsigned short)(u >> 16);
}
__device__ __forceinline__ float softplus_f(float v){
  return v > 15.f ? v : __logf(1.f + __expf(v));
}
__device__ __forceinline__ void pack8(const float* __restrict__ s,
                                      unsigned short* __restrict__ d){
  floatx4 v0 = *(const floatx4*)s;
  floatx4 v1 = *(const floatx4*)(s + 4);
  short8 r;
  r[0]=(short)f2b(v0[0]); r[1]=(short)f2b(v0[1]); r[2]=(short)f2b(v0[2]); r[3]=(short)f2b(v0[3]);
  r[4]=(short)f2b(v1[0]); r[5]=(short)f2b(v1[1]); r[6]=(short)f2b(v1[2]); r[7]=(short)f2b(v1[3]);
  *(short8*)d = r;
}

// ---------------- 1. prep ----------------
__global__ void prep_kernel(const float* __restrict__ x,
                            const float* __restrict__ W_B,
                            const float* __restrict__ W_C,
                            const float* __restrict__ W_dt,
                            const float* __restrict__ A_log,
                            const float* __restrict__ W_out,
                            unsigned short* __restrict__ xp,
                            unsigned short* __restrict__ Wp3,
                            unsigned short* __restrict__ Wop,
                            float* __restrict__ Aval){
  const int gid = blockIdx.x * blockDim.x + threadIdx.x;   // 0..98303
  if (gid < 2048) Aval[gid] = -__expf(A_log[gid]);
  if (gid < 65536){                               // x: 256 t-tiles, K=128
    int g = gid, tile = g >> 8, kk = (g >> 6) & 3, lane = g & 63;
    int q = lane >> 4, m = lane & 15;
    pack8(x + (size_t)(tile*16 + m)*DDIM + kk*32 + q*8, xp + (size_t)g*8);
  }
  if (gid < 98304){                               // W_B/W_dt/W_C: 128 n-tiles each
    int mat = gid >> 15, g = gid & 32767;
    const float* W = (mat == 0) ? W_B : (mat == 1 ? W_dt : W_C);
    int tile = g >> 8, kk = (g >> 6) & 3, lane = g & 63;
    int q = lane >> 4, m = lane & 15;
    pack8(W + (size_t)(tile*16 + m)*DDIM + kk*32 + q*8,
          Wp3 + (size_t)mat*262144 + (size_t)g*8);
  }
  if (gid < 32768){                               // W_out: 8 d-tiles, K=2048
    int g = gid, tile = g >> 12, kk = (g >> 6) & 63, lane = g & 63;
    int q = lane >> 4, m = lane & 15;
    pack8(W_out + (size_t)(tile*16 + m)*NDIM + kk*32 + q*8, Wop + (size_t)g*8);
  }
}

// ---------------- 2. fused proj + scan ----------------
// grid 256 = (b, nsl): b = bid>>7, nsl = bid&127 (16-n slice). 64 threads.
// mfma(xf, wf): D.row -> t_local (q*4+r), D.col -> n (m). h carried in iv reg.
__global__ __launch_bounds__(64) void fusedscan_kernel(
    const unsigned short* __restrict__ xp,
    const unsigned short* __restrict__ Wp3,
    const float* __restrict__ b_B,
    const float* __restrict__ b_dt,
    const float* __restrict__ b_C,
    const float* __restrict__ Aval,
    unsigned short* __restrict__ ybp){
  __shared__ unsigned short sYT[16*24];   // [t][n] transpose tile, row pad->24
  const int lane = threadIdx.x;           // 0..63
  const int m = lane & 15;
  const int q = lane >> 4;
  const int bid = blockIdx.x;
  const int b   = bid >> 7;
  const int nsl = bid & 127;
  const int n   = nsl*16 + m;

  // weights for this 16-n slice, held in registers (48 VGPRs)
  short8 wB[4], wD[4], wC[4];
#pragma unroll
  for (int kk = 0; kk < 4; ++kk){
    size_t o = (size_t)nsl*2048 + kk*512 + lane*8;
    wB[kk] = *(const short8*)(Wp3 + o);
    wD[kk] = *(const short8*)(Wp3 + 262144 + o);
    wC[kk] = *(const short8*)(Wp3 + 524288 + o);
  }
  const float bB = b_B[n], bD = b_dt[n], bC = b_C[n], Av = Aval[n];

  const unsigned short* xbase = xp + (size_t)b*TPB*2048;
  unsigned short* ybase = ybp + (size_t)b*TPB*32768
                        + (size_t)(nsl >> 1)*512 + (size_t)(nsl & 1)*256;
  float iv = 0.f;                         // carried state h for n (same in all q)

  short8 xc[4];
#pragma unroll
  for (int kk = 0; kk < 4; ++kk)
    xc[kk] = *(const short8*)(xbase + kk*512 + lane*8);

  for (int j = 0; j < TPB; ++j){
    // prefetch next tile's x fragments (wraps at end; harmless reload of tile 0)
    const int jn = (j + 1) & (TPB - 1);
    short8 xn[4];
#pragma unroll
    for (int kk = 0; kk < 4; ++kk)
      xn[kk] = *(const short8*)(xbase + (size_t)jn*2048 + kk*512 + lane*8);

    floatx4 aB = {0.f,0.f,0.f,0.f}, aD = aB, aC = aB;
#pragma unroll
    for (int kk = 0; kk < 4; ++kk){
      aB = __builtin_amdgcn_mfma_f32_16x16x32_bf16(xc[kk], wB[kk], aB, 0, 0, 0);
      aD = __builtin_amdgcn_mfma_f32_16x16x32_bf16(xc[kk], wD[kk], aD, 0, 0, 0);
      aC = __builtin_amdgcn_mfma_f32_16x16x32_bf16(xc[kk], wC[kk], aC, 0, 0, 0);
    }

    float Ar[4], Br[4], Cc[4];
#pragma unroll
    for (int r = 0; r < 4; ++r){
      float dtv = softplus_f(aD[r] + bD);
      Ar[r] = __expf(dtv * Av);
      Br[r] = dtv * (aB[r] + bB);
      Cc[r] = aC[r] + bC;
    }
    // compose lane's 4-token segment
    float P = Ar[0], H = Br[0];
#pragma unroll
    for (int r = 1; r < 4; ++r){ H = Ar[r]*H + Br[r]; P *= Ar[r]; }
    // inclusive scan across q (2 steps)
    float pp = __shfl(P, (lane - 16) & 63, 64);
    float hh = __shfl(H, (lane - 16) & 63, 64);
    if (q >= 1){ H = P*hh + H; P *= pp; }
    pp = __shfl(P, (lane - 32) & 63, 64);
    hh = __shfl(H, (lane - 32) & 63, 64);
    if (q >= 2){ H = P*hh + H; P *= pp; }
    // exclusive prefix for this q = inclusive of q-1
    float pe = __shfl(P, (lane - 16) & 63, 64);
    float he = __shfl(H, (lane - 16) & 63, 64);
    if (q == 0){ pe = 1.f; he = 0.f; }
    // full-tile inclusive (q==3) for carry update, broadcast to all q
    float pb = __shfl(P, m + 48, 64);
    float hb = __shfl(H, m + 48, 64);

    float h = pe*iv + he;
    unsigned short yy[4];
#pragma unroll
    for (int r = 0; r < 4; ++r){
      h = Ar[r]*h + Br[r];
      yy[r] = f2b(Cc[r]*h);
    }
    iv = pb*iv + hb;

    // transpose D-layout -> A-frag via LDS (within-wave, no barrier needed)
#pragma unroll
    for (int r = 0; r < 4; ++r)
      sYT[(q*4 + r)*24 + m] = yy[r];
    __builtin_amdgcn_s_waitcnt(0);   // lgkmcnt(0): drain LDS writes
    if (lane < 32){
      short8 v = *(const short8*)(sYT + (lane & 15)*24 + (lane >> 4)*8);
      *(short8*)(ybase + (size_t)j*32768 + (size_t)lane*8) = v;
    }
    __builtin_amdgcn_s_waitcnt(0);   // protect sYT reuse next iter

#pragma unroll
    for (int kk = 0; kk < 4; ++kk) xc[kk] = xn[kk];
  }
}

// ---------------- 3. output projection ----------------
// grid NTILE=256, block 256. Wave wv: kk in [wv*16, wv*16+16), all 8 d-tiles.
__global__ void outproj_kernel(const unsigned short* __restrict__ ybp,
                               const unsigned short* __restrict__ Wop,
                               const float* __restrict__ b_out,
                               float* __restrict__ out){
  __shared__ float red[4*2048];
  const int tid  = threadIdx.x;
  const int lane = tid & 63;
  const int wv   = tid >> 6;
  const int m    = lane & 15;
  const int q    = lane >> 4;
  const int tile = blockIdx.x;

  floatx4 acc[8];
#pragma unroll
  for (int dt = 0; dt < 8; ++dt) acc[dt] = (floatx4){0.f,0.f,0.f,0.f};

  const unsigned short* aP = ybp + (size_t)tile*32768 + lane*8;
  const unsigned short* bP = Wop + (size_t)lane*8;
#pragma unroll 4
  for (int kk = wv*16; kk < wv*16 + 16; ++kk){
    short8 af = *(const short8*)(aP + (size_t)kk*512);
#pragma unroll
    for (int dt = 0; dt < 8; ++dt){
      short8 bf = *(const short8*)(bP + (size_t)dt*32768 + (size_t)kk*512);
      acc[dt] = __builtin_amdgcn_mfma_f32_16x16x32_bf16(af, bf, acc[dt], 0, 0, 0);
    }
  }
#pragma unroll
  for (int dt = 0; dt < 8; ++dt)
#pragma unroll
    for (int r = 0; r < 4; ++r)
      red[wv*2048 + (q*4 + r)*128 + dt*16 + m] = acc[dt][r];
  __syncthreads();
#pragma unroll
  for (int i = 0; i < 8; ++i){
    int idx = i*256 + tid;                        // 0..2047 = tl*128 + d
    float s = red[idx] + red[2048 + idx] + red[4096 + idx] + red[6144 + idx];
    int tl = idx >> 7, d = idx & 127;
    out[(size_t)(tile*16 + tl)*DDIM + d] = s + b_out[d];
  }
}

extern "C" void kernel_launch(void* const* d_in, const int* in_sizes, int n_in,
                              void* d_out, int out_size, void* d_ws, size_t ws_size,
                              hipStream_t stream) {
  const float* x     = (const float*)d_in[0];
  const float* W_B   = (const float*)d_in[1];
  const float* b_B   = (const float*)d_in[2];
  const float* W_C   = (const float*)d_in[3];
  const float* b_C   = (const float*)d_in[4];
  const float* W_dt  = (const float*)d_in[5];
  const float* b_dt  = (const float*)d_in[6];
  const float* A_log = (const float*)d_in[7];
  const float* W_out = (const float*)d_in[8];
  const float* b_out = (const float*)d_in[9];
  float* out = (float*)d_out;

  char* w = (char*)d_ws;
  unsigned short* xp    = (unsigned short*)(w + 0x0000000);  // 1 MB
  unsigned short* Wp3   = (unsigned short*)(w + 0x0100000);  // 1.5 MB
  unsigned short* Wop   = (unsigned short*)(w + 0x0280000);  // 0.5 MB
  float*          Aval  = (float*)         (w + 0x0300000);  // 8 KB
  unsigned short* ybp   = (unsigned short*)(w + 0x0310000);  // 16 MB

  prep_kernel<<<384, 256, 0, stream>>>(
      x, W_B, W_C, W_dt, A_log, W_out, xp, Wp3, Wop, Aval);

  fusedscan_kernel<<<256, 64, 0, stream>>>(
      xp, Wp3, b_B, b_dt, b_C, Aval, ybp);

  outproj_kernel<<<NTILE, 256, 0, stream>>>(ybp, Wop, b_out, out);
}

// Round 6
// 132.627 us; speedup vs baseline: 1.2953x; 1.2953x over previous
//
#include <hip/hip_runtime.h>

// Rec1_43748536877661 — diagonal SSM block, MI355X gfx950.
// B=2,S=2048,D=128,N=2048. fp32 in/out, bf16 MFMA compute (tol 2.14e-2).
// R6: single wide proj pass emits y_local + coef (=C*prefix_a) + per-tile (P,H);
// carry computes per-tile init; outproj applies fixup y = y_local + coef*init
// inline before MFMA. No recompute pass. 4 kernels:
//  1. prep      pack W_B/dt/C,W_out fragment-linear bf16; Aval=-exp(A_log)
//  2. projscan  3 GEMMs + tile scan(init=0) -> ybp, coefp (bf16 A-frag), PH
//  3. carry     2-level scan over 128 tiles/chain -> per-tile init h0
//  4. outproj   (y_local + coef*init) @ W_out^T + b_out -> fp32 out

#define BB 2
#define SS 2048
#define DDIM 128
#define NDIM 2048
#define TT (BB*SS)        // 4096 tokens
#define NTILE (TT/16)     // 256 t-tiles
#define TPB 128           // t-tiles per batch chain

typedef short short8 __attribute__((ext_vector_type(8)));
typedef float floatx4 __attribute__((ext_vector_type(4)));

__device__ __forceinline__ unsigned short f2b(float f){
  unsigned u = __float_as_uint(f);
  u += 0x7FFFu + ((u >> 16) & 1u);
  return (unsigned short)(u >> 16);
}
__device__ __forceinline__ float b2f(unsigned short h){
  return __uint_as_float(((unsigned)h) << 16);
}
__device__ __forceinline__ float softplus_f(float v){
  return v > 15.f ? v : __logf(1.f + __expf(v));
}
__device__ __forceinline__ void pack8(const float* __restrict__ s,
                                      unsigned short* __restrict__ d){
  floatx4 v0 = *(const floatx4*)s;
  floatx4 v1 = *(const floatx4*)(s + 4);
  short8 r;
  r[0]=(short)f2b(v0[0]); r[1]=(short)f2b(v0[1]); r[2]=(short)f2b(v0[2]); r[3]=(short)f2b(v0[3]);
  r[4]=(short)f2b(v1[0]); r[5]=(short)f2b(v1[1]); r[6]=(short)f2b(v1[2]); r[7]=(short)f2b(v1[3]);
  *(short8*)d = r;
}

// ---------------- 1. prep: weights + Aval ----------------
__global__ void prep_kernel(const float* __restrict__ W_B,
                            const float* __restrict__ W_C,
                            const float* __restrict__ W_dt,
                            const float* __restrict__ A_log,
                            const float* __restrict__ W_out,
                            unsigned short* __restrict__ Wp3,
                            unsigned short* __restrict__ Wop,
                            float* __restrict__ Aval){
  const int gid = blockIdx.x * blockDim.x + threadIdx.x;   // 0..98303
  if (gid < 2048) Aval[gid] = -__expf(A_log[gid]);
  if (gid < 98304){                               // W_B/W_dt/W_C: 128 n-tiles each
    int mat = gid >> 15, g = gid & 32767;
    const float* W = (mat == 0) ? W_B : (mat == 1 ? W_dt : W_C);
    int tile = g >> 8, kk = (g >> 6) & 3, lane = g & 63;
    int q = lane >> 4, m = lane & 15;
    pack8(W + (size_t)(tile*16 + m)*DDIM + kk*32 + q*8,
          Wp3 + (size_t)mat*262144 + (size_t)g*8);
  }
  if (gid < 32768){                               // W_out: 8 d-tiles, K=2048
    int g = gid, tile = g >> 12, kk = (g >> 6) & 63, lane = g & 63;
    int q = lane >> 4, m = lane & 15;
    pack8(W_out + (size_t)(tile*16 + m)*NDIM + kk*32 + q*8, Wop + (size_t)g*8);
  }
}

// ---------------- 2. projscan: 3 GEMMs + tile scan -> ybp, coefp, PH ----------
// grid (TT/64=64, NDIM/32=64), block 256. mfma(xf,wf): D.row->t(q*4+r), D.col->n(m).
__global__ void projscan_kernel(const float* __restrict__ xG,
                                const unsigned short* __restrict__ Wp3,
                                const float* __restrict__ b_B,
                                const float* __restrict__ b_dt,
                                const float* __restrict__ b_C,
                                const float* __restrict__ Aval,
                                unsigned short* __restrict__ ybp,
                                unsigned short* __restrict__ coefp,
                                float2* __restrict__ PH){
  __shared__ unsigned short sW[3*4096];      // 24 KB: [mat][nt<2][kk<4][lane][8]
  __shared__ unsigned short sYT[4][16*40];   // per-wave transpose [t][n], pad 40
  __shared__ unsigned short sCT[4][16*40];
  const int tid  = threadIdx.x;
  const int lane = tid & 63;
  const int wv   = tid >> 6;
  const int m    = lane & 15;
  const int q    = lane >> 4;

  // stage packed weights: 3 mats x 2 n-tiles x 2048 ushort
  for (int i = tid; i < 1536; i += 256){
    int mat = i >> 9, rem = i & 511;
    *(short8*)(sW + mat*4096 + rem*8) =
        *(const short8*)(Wp3 + (size_t)mat*262144 + (size_t)blockIdx.y*4096 + rem*8);
  }
  __syncthreads();

  const int tileT = blockIdx.x*4 + wv;
  // x fragments direct from fp32 global: A[m][kk*32+q*8+j]
  short8 xf[4];
  const float* xr = xG + (size_t)(tileT*16 + m)*DDIM + q*8;
#pragma unroll
  for (int kk = 0; kk < 4; ++kk){
    floatx4 u = *(const floatx4*)(xr + kk*32);
    floatx4 v = *(const floatx4*)(xr + kk*32 + 4);
    short8 t;
    t[0]=(short)f2b(u[0]); t[1]=(short)f2b(u[1]); t[2]=(short)f2b(u[2]); t[3]=(short)f2b(u[3]);
    t[4]=(short)f2b(v[0]); t[5]=(short)f2b(v[1]); t[6]=(short)f2b(v[2]); t[7]=(short)f2b(v[3]);
    xf[kk] = t;
  }

  floatx4 acc[3][2];
#pragma unroll
  for (int mat = 0; mat < 3; ++mat)
#pragma unroll
    for (int nt = 0; nt < 2; ++nt)
      acc[mat][nt] = (floatx4){0.f,0.f,0.f,0.f};
#pragma unroll
  for (int nt = 0; nt < 2; ++nt)
#pragma unroll
    for (int kk = 0; kk < 4; ++kk){
      short8 wB = *(const short8*)(sW +         nt*2048 + kk*512 + lane*8);
      short8 wD = *(const short8*)(sW + 4096 +  nt*2048 + kk*512 + lane*8);
      short8 wC = *(const short8*)(sW + 8192 +  nt*2048 + kk*512 + lane*8);
      acc[0][nt] = __builtin_amdgcn_mfma_f32_16x16x32_bf16(xf[kk], wB, acc[0][nt], 0, 0, 0);
      acc[1][nt] = __builtin_amdgcn_mfma_f32_16x16x32_bf16(xf[kk], wD, acc[1][nt], 0, 0, 0);
      acc[2][nt] = __builtin_amdgcn_mfma_f32_16x16x32_bf16(xf[kk], wC, acc[2][nt], 0, 0, 0);
    }

  const int n0 = blockIdx.y*32;
  unsigned short ybuf[8], cbuf[8];
#pragma unroll
  for (int nt = 0; nt < 2; ++nt){
    const int n = n0 + nt*16 + m;
    const float bB = b_B[n], bD = b_dt[n], bC = b_C[n], Av = Aval[n];
    float Ar[4], Br[4], Cc[4];
#pragma unroll
    for (int r = 0; r < 4; ++r){
      float dtv = softplus_f(acc[1][nt][r] + bD);
      Ar[r] = __expf(dtv * Av);
      Br[r] = dtv * (acc[0][nt][r] + bB);
      Cc[r] = acc[2][nt][r] + bC;
    }
    // compose lane's 4-token segment
    float P = Ar[0], H = Br[0];
#pragma unroll
    for (int r = 1; r < 4; ++r){ H = Ar[r]*H + Br[r]; P *= Ar[r]; }
    // inclusive scan across q (2 steps)
    float pp = __shfl(P, (lane - 16) & 63, 64);
    float hh = __shfl(H, (lane - 16) & 63, 64);
    if (q >= 1){ H = P*hh + H; P *= pp; }
    pp = __shfl(P, (lane - 32) & 63, 64);
    hh = __shfl(H, (lane - 32) & 63, 64);
    if (q >= 2){ H = P*hh + H; P *= pp; }
    // exclusive prefix for this q = inclusive of q-1
    float pe = __shfl(P, (lane - 16) & 63, 64);
    float he = __shfl(H, (lane - 16) & 63, 64);
    if (q == 0){ pe = 1.f; he = 0.f; }
    // local scan with init=0; coef = C * running prefix_a
    float h = he, pa = pe;
#pragma unroll
    for (int r = 0; r < 4; ++r){
      h = Ar[r]*h + Br[r];
      pa *= Ar[r];
      ybuf[nt*4 + r] = f2b(Cc[r]*h);
      cbuf[nt*4 + r] = f2b(Cc[r]*pa);
    }
    if (q == 3){
      float2 ph; ph.x = P; ph.y = H;
      PH[(size_t)tileT*NDIM + n] = ph;
    }
  }

  // transpose D-layout (t in q/regs) -> A-frag layout via per-wave LDS
#pragma unroll
  for (int nt = 0; nt < 2; ++nt)
#pragma unroll
    for (int r = 0; r < 4; ++r){
      sYT[wv][(q*4 + r)*40 + nt*16 + m] = ybuf[nt*4 + r];
      sCT[wv][(q*4 + r)*40 + nt*16 + m] = cbuf[nt*4 + r];
    }
  short8 yv = *(const short8*)&sYT[wv][m*40 + q*8];
  short8 cv = *(const short8*)&sCT[wv][m*40 + q*8];
  size_t o = (size_t)tileT*32768 + (size_t)blockIdx.y*512 + (size_t)lane*8;
  *(short8*)(ybp   + o) = yv;
  *(short8*)(coefp + o) = cv;
}

// ---------------- 3. carry: 2-level block-parallel scan ----------------
// grid 128 x 256. Block = 32 chains (one b, 32 consecutive n); thread
// (c=tid&31, s=tid>>5) handles segment s (16 tiles) of chain c.
__global__ void carry_kernel(const float2* __restrict__ PH,
                             float* __restrict__ initb){
  __shared__ float sP[8][32], sH[8][32], eH[8][32];
  const int tid = threadIdx.x;
  const int c = tid & 31;
  const int s = tid >> 5;
  const int b = blockIdx.x >> 6;
  const int n = (blockIdx.x & 63)*32 + c;

  float Pj[16], Hj[16];
  size_t base = ((size_t)(b*TPB + s*16))*NDIM + n;
#pragma unroll
  for (int j = 0; j < 16; ++j){
    float2 ph = PH[base + (size_t)j*NDIM];
    Pj[j] = ph.x; Hj[j] = ph.y;
  }
  float P = Pj[0], H = Hj[0];
#pragma unroll
  for (int j = 1; j < 16; ++j){ H = Pj[j]*H + Hj[j]; P *= Pj[j]; }
  sP[s][c] = P; sH[s][c] = H;
  __syncthreads();
  if (tid < 32){
    float p = 1.f, h = 0.f;
#pragma unroll
    for (int ss = 0; ss < 8; ++ss){
      eH[ss][tid] = h;
      h = sP[ss][tid]*h + sH[ss][tid];
      p = sP[ss][tid]*p;
    }
  }
  __syncthreads();
  float h = eH[s][c];          // chain init is 0 => segment init = eH
#pragma unroll
  for (int j = 0; j < 16; ++j){
    initb[base + (size_t)j*NDIM] = h;
    h = Pj[j]*h + Hj[j];
  }
}

// ---------------- 4. outproj with fixup ----------------
// grid NTILE=256, block 256. Wave wv: kk in [wv*16, wv*16+16), all 8 d-tiles.
// af = y_local + coef*init, built inline.
__global__ void outproj_kernel(const unsigned short* __restrict__ ybp,
                               const unsigned short* __restrict__ coefp,
                               const float* __restrict__ initb,
                               const unsigned short* __restrict__ Wop,
                               const float* __restrict__ b_out,
                               float* __restrict__ out){
  __shared__ float red[4*2048];
  const int tid  = threadIdx.x;
  const int lane = tid & 63;
  const int wv   = tid >> 6;
  const int m    = lane & 15;
  const int q    = lane >> 4;
  const int tile = blockIdx.x;

  floatx4 acc[8];
#pragma unroll
  for (int dt = 0; dt < 8; ++dt) acc[dt] = (floatx4){0.f,0.f,0.f,0.f};

  const unsigned short* aP = ybp   + (size_t)tile*32768 + lane*8;
  const unsigned short* cP = coefp + (size_t)tile*32768 + lane*8;
  const float*          iB = initb + (size_t)tile*NDIM + q*8;
  const unsigned short* bP = Wop + (size_t)lane*8;
#pragma unroll 4
  for (int kk = wv*16; kk < wv*16 + 16; ++kk){
    short8 yl = *(const short8*)(aP + (size_t)kk*512);
    short8 cf = *(const short8*)(cP + (size_t)kk*512);
    floatx4 i0 = *(const floatx4*)(iB + kk*32);
    floatx4 i1 = *(const floatx4*)(iB + kk*32 + 4);
    short8 af;
#pragma unroll
    for (int j = 0; j < 4; ++j)
      af[j] = (short)f2b(b2f((unsigned short)yl[j]) + b2f((unsigned short)cf[j])*i0[j]);
#pragma unroll
    for (int j = 0; j < 4; ++j)
      af[4+j] = (short)f2b(b2f((unsigned short)yl[4+j]) + b2f((unsigned short)cf[4+j])*i1[j]);
#pragma unroll
    for (int dt = 0; dt < 8; ++dt){
      short8 bf = *(const short8*)(bP + (size_t)dt*32768 + (size_t)kk*512);
      acc[dt] = __builtin_amdgcn_mfma_f32_16x16x32_bf16(af, bf, acc[dt], 0, 0, 0);
    }
  }
#pragma unroll
  for (int dt = 0; dt < 8; ++dt)
#pragma unroll
    for (int r = 0; r < 4; ++r)
      red[wv*2048 + (q*4 + r)*128 + dt*16 + m] = acc[dt][r];
  __syncthreads();
#pragma unroll
  for (int i = 0; i < 8; ++i){
    int idx = i*256 + tid;                        // 0..2047 = tl*128 + d
    float s = red[idx] + red[2048 + idx] + red[4096 + idx] + red[6144 + idx];
    int tl = idx >> 7, d = idx & 127;
    out[(size_t)(tile*16 + tl)*DDIM + d] = s + b_out[d];
  }
}

extern "C" void kernel_launch(void* const* d_in, const int* in_sizes, int n_in,
                              void* d_out, int out_size, void* d_ws, size_t ws_size,
                              hipStream_t stream) {
  const float* x     = (const float*)d_in[0];
  const float* W_B   = (const float*)d_in[1];
  const float* b_B   = (const float*)d_in[2];
  const float* W_C   = (const float*)d_in[3];
  const float* b_C   = (const float*)d_in[4];
  const float* W_dt  = (const float*)d_in[5];
  const float* b_dt  = (const float*)d_in[6];
  const float* A_log = (const float*)d_in[7];
  const float* W_out = (const float*)d_in[8];
  const float* b_out = (const float*)d_in[9];
  float* out = (float*)d_out;

  char* w = (char*)d_ws;
  unsigned short* Wp3   = (unsigned short*)(w + 0x0000000);  // 1.5 MB
  unsigned short* Wop   = (unsigned short*)(w + 0x0180000);  // 0.5 MB
  float*          Aval  = (float*)         (w + 0x0200000);  // 8 KB
  float2*         PH    = (float2*)        (w + 0x0210000);  // 4 MB
  float*          initb = (float*)         (w + 0x0610000);  // 2 MB
  unsigned short* ybp   = (unsigned short*)(w + 0x0810000);  // 16 MB
  unsigned short* coefp = (unsigned short*)(w + 0x1810000);  // 16 MB
  // total ~40 MB

  prep_kernel<<<384, 256, 0, stream>>>(
      W_B, W_C, W_dt, A_log, W_out, Wp3, Wop, Aval);

  projscan_kernel<<<dim3(TT/64, NDIM/32), 256, 0, stream>>>(
      x, Wp3, b_B, b_dt, b_C, Aval, ybp, coefp, PH);

  carry_kernel<<<128, 256, 0, stream>>>(PH, initb);

  outproj_kernel<<<NTILE, 256, 0, stream>>>(
      ybp, coefp, initb, Wop, b_out, out);
}